// Round 2
// baseline (484.787 us; speedup 1.0000x reference)
//
#include <hip/hip_runtime.h>

typedef __attribute__((ext_vector_type(8))) short short8;
typedef __attribute__((ext_vector_type(4))) float f32x4;

#define LOG2E 1.44269504f

__device__ __forceinline__ short f2bf(float f) {
  unsigned u = __builtin_bit_cast(unsigned, f);
  u += 0x7fffu + ((u >> 16) & 1u);   // round-to-nearest-even
  return (short)(u >> 16);
}

// ---------------- kernel A: w1 = W@a1, w2 = W@a2 (fp32) ----------------
__global__ void gat_wvec(const float* __restrict__ W, const float* __restrict__ a1,
                         const float* __restrict__ a2, float* __restrict__ w1,
                         float* __restrict__ w2) {
  __shared__ float a1f[256], a2f[256];
  const int tid = threadIdx.x;
  a1f[tid] = a1[tid];
  a2f[tid] = a2[tid];
  __syncthreads();
  float s1 = 0.f, s2 = 0.f;
  const float4* wr = (const float4*)(W + (size_t)tid * 256);
  for (int d0 = 0; d0 < 64; ++d0) {
    float4 v = wr[d0];
    s1 += v.x * a1f[d0 * 4] + v.y * a1f[d0 * 4 + 1] + v.z * a1f[d0 * 4 + 2] + v.w * a1f[d0 * 4 + 3];
    s2 += v.x * a2f[d0 * 4] + v.y * a2f[d0 * 4 + 1] + v.z * a2f[d0 * 4 + 2] + v.w * a2f[d0 * 4 + 3];
  }
  w1[tid] = s1;
  w2[tid] = s2;
}

// ------------- f32 -> bf16 convert + transpose: dst[b][c][r] = bf16(src[b][r][c]) -------------
__global__ void convT(const float* __restrict__ src, short* __restrict__ dst,
                      int R, int C) {
  __shared__ short T[64][72];
  const int tid = threadIdx.x;
  const int bc = blockIdx.x, br = blockIdx.y, bb = blockIdx.z;
  const float* s = src + (size_t)bb * R * C;
  short* d = dst + (size_t)bb * R * C;
  const int rr = tid >> 2, cc = (tid & 3) << 4;
  const float4* sp = (const float4*)(s + (size_t)(br * 64 + rr) * C + bc * 64 + cc);
  alignas(16) short v[16];
#pragma unroll
  for (int g = 0; g < 4; ++g) {
    float4 x = sp[g];
    v[g * 4 + 0] = f2bf(x.x);
    v[g * 4 + 1] = f2bf(x.y);
    v[g * 4 + 2] = f2bf(x.z);
    v[g * 4 + 3] = f2bf(x.w);
  }
  *(short8*)&T[rr][cc] = *(short8*)&v[0];
  *(short8*)&T[rr][cc + 8] = *(short8*)&v[8];
  __syncthreads();
#pragma unroll
  for (int j = 0; j < 16; ++j) v[j] = T[cc + j][rr];
  short8* dp = (short8*)(d + (size_t)(bc * 64 + rr) * R + br * 64 + cc);
  dp[0] = *(short8*)&v[0];
  dp[1] = *(short8*)&v[8];
}

// ---------------- kernel B: Ax/Ay (one wave per row, f32 feat) ----------------
__global__ void gat_axay(const float* __restrict__ feat, const float* __restrict__ w1,
                         const float* __restrict__ w2, float* __restrict__ Ax,
                         float* __restrict__ Ay) {
  const int lane = threadIdx.x & 63;
  const int row = blockIdx.x * 4 + (threadIdx.x >> 6);
  float4 fv = *(const float4*)(feat + (size_t)row * 256 + lane * 4);
  const float4 w1v = *(const float4*)(w1 + lane * 4);
  const float4 w2v = *(const float4*)(w2 + lane * 4);
  float s1 = fv.x * w1v.x + fv.y * w1v.y + fv.z * w1v.z + fv.w * w1v.w;
  float s2 = fv.x * w2v.x + fv.y * w2v.y + fv.z * w2v.z + fv.w * w2v.w;
#pragma unroll
  for (int off = 32; off >= 1; off >>= 1) {
    s1 += __shfl_xor(s1, off);
    s2 += __shfl_xor(s2, off);
  }
  if (lane == 0) { Ax[row] = s1; Ay[row] = s2; }
}

// ---------------- kernel B2: per-batch max of Ax ----------------
__global__ void gat_max(const float* __restrict__ Ax, float* __restrict__ Mb) {
  __shared__ float red[256];
  const int b = blockIdx.x, tid = threadIdx.x;
  float m = -3.4e38f;
  for (int i = tid; i < 4096; i += 256) m = fmaxf(m, Ax[b * 4096 + i]);
  red[tid] = m;
  __syncthreads();
  for (int s = 128; s > 0; s >>= 1) {
    if (tid < s) red[tid] = fmaxf(red[tid], red[tid + s]);
    __syncthreads();
  }
  if (tid == 0) Mb[b] = red[0];
}

// ---------------- kernel C: fused masked-softmax(rank-1 scores) @ feat ----------------
// grid: 512 = b(4) x i-tile(64) x j-split(2); block 256 = 4 waves, wave owns 64 cols of D
__global__ __launch_bounds__(256, 2) void gat_attn(
    const short* __restrict__ featT,  // [4][256][4096] bf16
    const int* __restrict__ adj,      // [4][4096][4096]
    const float* __restrict__ Ax, const float* __restrict__ Ay,
    const float* __restrict__ Mb,
    float* __restrict__ Opart,        // [2][16384][256] f32
    float* __restrict__ lpart)        // [2][16384] f32
{
  __shared__ short Pbuf[2][64][72];   // padded stride 72 (144 B = 9x16B)
  __shared__ float lsbuf[256];
  const int tid = threadIdx.x;
  const int blk = blockIdx.x;
  const int s = blk & 1;
  const int it = (blk >> 1) & 63;
  const int b = blk >> 7;
  const int i0 = it << 6;
  const int jbase = s << 11;

  const int r = tid >> 2;            // local row 0..63
  const int c0 = (tid & 3) << 4;     // local col base {0,16,32,48}

  const float ay = Ay[b * 4096 + i0 + r];
  float mr = ay + Mb[b];
  mr = mr > 0.f ? mr : 0.2f * mr;    // uniform upper bound on this row's scores

  const int lane = tid & 63;
  const int w = tid >> 6;
  const int n0 = w << 6;
  const int l15 = lane & 15;
  const int q = lane >> 4;

  f32x4 acc[4][4];
#pragma unroll
  for (int i = 0; i < 4; ++i)
#pragma unroll
    for (int j = 0; j < 4; ++j) acc[i][j] = (f32x4){0.f, 0.f, 0.f, 0.f};

  float lsum = 0.f;

  const int4* adjp = (const int4*)(adj + ((size_t)(b * 4096 + i0 + r)) * 4096 + jbase + c0);
  const float4* axp = (const float4*)(Ax + b * 4096 + jbase + c0);
  const short* ftb = featT + ((size_t)(b * 256 + n0 + l15)) * 4096 + jbase + q * 8;

  int4 adv[4];
  float4 axv[4];
#pragma unroll
  for (int g = 0; g < 4; ++g) { adv[g] = adjp[g]; axv[g] = axp[g]; }

  for (int c = 0; c < 32; ++c) {
    // ---- phase 1: P tile (exp of masked lrelu scores), bf16 into LDS ----
    alignas(16) short pk[16];
#pragma unroll
    for (int g = 0; g < 4; ++g) {
      const int* ai = (const int*)&adv[g];
      const float* af = (const float*)&axv[g];
#pragma unroll
      for (int u = 0; u < 4; ++u) {
        float lg = af[u] + ay;
        float e = lg > 0.f ? lg : 0.2f * lg;
        e = ai[u] > 0 ? e : -9e15f;
        float p = __builtin_amdgcn_exp2f((e - mr) * LOG2E);
        lsum += p;
        pk[g * 4 + u] = f2bf(p);
      }
    }
    {
      short8* dst = (short8*)&Pbuf[c & 1][r][c0];
      dst[0] = *(short8*)&pk[0];
      dst[1] = *(short8*)&pk[8];
    }
    __syncthreads();

    // prefetch next chunk's adj/Ax (overlaps MFMA below, no barrier between)
    if (c < 31) {
#pragma unroll
      for (int g = 0; g < 4; ++g) {
        adv[g] = adjp[(c + 1) * 16 + g];
        axv[g] = axp[(c + 1) * 16 + g];
      }
    }

    // ---- phase 2: MFMA  O += P(64x64) * feat(64x64cols per wave) ----
    const int j0 = c << 6;
#pragma unroll
    for (int k0 = 0; k0 < 64; k0 += 32) {
      short8 afr[4];
#pragma unroll
      for (int rt = 0; rt < 4; ++rt)
        afr[rt] = *(const short8*)&Pbuf[c & 1][rt * 16 + l15][k0 + q * 8];
#pragma unroll
      for (int ct = 0; ct < 4; ++ct) {
        short8 bfr = *(const short8*)(ftb + (size_t)ct * 16 * 4096 + j0 + k0);
#pragma unroll
        for (int rt = 0; rt < 4; ++rt)
          acc[rt][ct] = __builtin_amdgcn_mfma_f32_16x16x32_bf16(afr[rt], bfr, acc[rt][ct], 0, 0, 0);
      }
    }
  }

  // ---- epilogue: partial row-sums + partial O ----
  lsbuf[tid] = lsum;
  __syncthreads();
  if (tid < 64) {
    float t = lsbuf[tid * 4] + lsbuf[tid * 4 + 1] + lsbuf[tid * 4 + 2] + lsbuf[tid * 4 + 3];
    lpart[(size_t)s * 16384 + b * 4096 + i0 + tid] = t;
  }
  float* Od = Opart + (size_t)s * 16384 * 256;
#pragma unroll
  for (int rt = 0; rt < 4; ++rt)
#pragma unroll
    for (int reg = 0; reg < 4; ++reg) {
      int row = i0 + rt * 16 + q * 4 + reg;  // C/D layout: row = quad*4 + reg
      float* orow = Od + ((size_t)(b * 4096 + row)) * 256 + n0 + l15;
#pragma unroll
      for (int ct = 0; ct < 4; ++ct) orow[ct * 16] = acc[rt][ct][reg];
    }
}

// ---------------- kernel D: h_out = ((O1+O2)/l) @ W, ELU, f32 store ----------------
__global__ __launch_bounds__(256, 2) void gat_out(
    const float* __restrict__ O,   // [2][16384][256]
    const float* __restrict__ lp,  // [2][16384]
    const short* __restrict__ WT,  // [256][256] bf16 (W transposed)
    float* __restrict__ out)       // [16384][256] f32
{
  const int tid = threadIdx.x;
  const int lane = tid & 63;
  const int w = tid >> 6;
  const int r0 = blockIdx.x << 6;
  const int n0 = w << 6;
  const int l15 = lane & 15;
  const int q = lane >> 4;

  f32x4 acc[4][4];
#pragma unroll
  for (int i = 0; i < 4; ++i)
#pragma unroll
    for (int j = 0; j < 4; ++j) acc[i][j] = (f32x4){0.f, 0.f, 0.f, 0.f};

  float linv[4];
#pragma unroll
  for (int rt = 0; rt < 4; ++rt) {
    int row = r0 + rt * 16 + l15;
    float l = lp[row] + lp[16384 + row];
    linv[rt] = l > 0.f ? 1.f / l : 0.f;
  }
  const float* O2 = O + (size_t)16384 * 256;

#pragma unroll 2
  for (int k0 = 0; k0 < 256; k0 += 32) {
    short8 afr[4];
#pragma unroll
    for (int rt = 0; rt < 4; ++rt) {
      size_t off = (size_t)(r0 + rt * 16 + l15) * 256 + k0 + q * 8;
      f32x4 h0 = *(const f32x4*)(O + off) + *(const f32x4*)(O2 + off);
      f32x4 h1 = *(const f32x4*)(O + off + 4) + *(const f32x4*)(O2 + off + 4);
      h0 *= linv[rt];
      h1 *= linv[rt];
      alignas(16) short p[8];
#pragma unroll
      for (int j = 0; j < 4; ++j) { p[j] = f2bf(h0[j]); p[4 + j] = f2bf(h1[j]); }
      afr[rt] = *(short8*)p;
    }
#pragma unroll
    for (int ct = 0; ct < 4; ++ct) {
      short8 bfr = *(const short8*)(WT + (size_t)(n0 + ct * 16 + l15) * 256 + k0 + q * 8);
#pragma unroll
      for (int rt = 0; rt < 4; ++rt)
        acc[rt][ct] = __builtin_amdgcn_mfma_f32_16x16x32_bf16(afr[rt], bfr, acc[rt][ct], 0, 0, 0);
    }
  }
#pragma unroll
  for (int rt = 0; rt < 4; ++rt)
#pragma unroll
    for (int reg = 0; reg < 4; ++reg) {
      int row = r0 + rt * 16 + q * 4 + reg;
#pragma unroll
      for (int ct = 0; ct < 4; ++ct) {
        float v = acc[rt][ct][reg];
        float o = v > 0.f ? v : (__builtin_amdgcn_exp2f(v * LOG2E) - 1.f);
        out[(size_t)row * 256 + n0 + ct * 16 + l15] = o;
      }
    }
}

extern "C" void kernel_launch(void* const* d_in, const int* in_sizes, int n_in,
                              void* d_out, int out_size, void* d_ws, size_t ws_size,
                              hipStream_t stream) {
  (void)in_sizes; (void)n_in; (void)out_size; (void)ws_size;
  const float* feat = (const float*)d_in[0];
  const int* adj = (const int*)d_in[1];
  const float* W = (const float*)d_in[2];
  const float* a1 = (const float*)d_in[3];
  const float* a2 = (const float*)d_in[4];
  float* out = (float*)d_out;

  char* ws = (char*)d_ws;
  short* featT = (short*)ws;                   // 8,388,608 B  [4][256][4096] bf16
  float* Opart = (float*)(ws + 8388608);       // 33,554,432 B [2][16384][256] f32
  short* WT    = (short*)(ws + 41943040);      // 131,072 B
  float* w1    = (float*)(ws + 42074112);      // 1 KB
  float* w2    = (float*)(ws + 42075136);      // 1 KB
  float* Ax    = (float*)(ws + 42076160);      // 64 KB
  float* Ay    = (float*)(ws + 42141696);      // 64 KB
  float* lpart = (float*)(ws + 42207232);      // 128 KB
  float* Mb    = (float*)(ws + 42338304);      // 16 B

  hipLaunchKernelGGL(gat_wvec, dim3(1), dim3(256), 0, stream, W, a1, a2, w1, w2);
  hipLaunchKernelGGL(convT, dim3(4, 4, 1), dim3(256), 0, stream, W, WT, 256, 256);
  hipLaunchKernelGGL(convT, dim3(4, 64, 4), dim3(256), 0, stream, feat, featT, 4096, 256);
  hipLaunchKernelGGL(gat_axay, dim3(4096), dim3(256), 0, stream, feat, w1, w2, Ax, Ay);
  hipLaunchKernelGGL(gat_max, dim3(4), dim3(256), 0, stream, Ax, Mb);
  hipLaunchKernelGGL(gat_attn, dim3(512), dim3(256), 0, stream, featT, adj, Ax, Ay, Mb, Opart, lpart);
  hipLaunchKernelGGL(gat_out, dim3(256), dim3(256), 0, stream, Opart, lpart, WT, out);
}